// Round 1
// baseline (1014.374 us; speedup 1.0000x reference)
//
#include <hip/hip_runtime.h>
#include <hip/hip_fp16.h>

#define EMB  128
#define HID  64
#define NH   200   // history length H
#define BT   256   // threads per block
#define LDH  130   // fp16 LDS row stride (pad 2 -> bank-conflict-free 2-way)

// One block per batch row b.
//  - stage hist[b] (200x128 fp32) -> LDS fp16 (52 KB)   [single HBM read]
//  - c1 = b1 + cand[b] @ W1[128:256]  (h-invariant half of layer 1)
//  - lane h = tid < 200: 3-layer MLP score, weights via wave-uniform scalar loads
//  - wave 0: masked softmax over 200
//  - all threads: aggregation from fp16 LDS copy
__global__ __launch_bounds__(BT, 3) void attn_agg_kernel(
    const float* __restrict__ hist,   // [B, NH, EMB]
    const float* __restrict__ cand,   // [B, EMB]
    const float* __restrict__ W1,     // [2*EMB, HID]
    const float* __restrict__ b1,     // [HID]
    const float* __restrict__ W2,     // [HID, HID/2]
    const float* __restrict__ b2,     // [HID/2]
    const float* __restrict__ W3,     // [HID/2, 1]
    const float* __restrict__ b3,     // [1]
    const int*   __restrict__ mask,   // [B, NH]
    float* __restrict__ out_agg,      // [B, EMB]
    float* __restrict__ out_attn)     // [B, NH]
{
    __shared__ __half hist_s[NH * LDH];   // 52,000 B
    __shared__ float  c1_s[HID];          //    256 B
    __shared__ float  attn_s[NH];         //    800 B

    const int b   = blockIdx.x;
    const int tid = threadIdx.x;
    const float* hb = hist + (size_t)b * (NH * EMB);

    // ---- stage hist[b] -> LDS fp16 (25 iterations of float4 per thread) ----
    for (int i = tid; i < NH * EMB / 4; i += BT) {
        int h  = i >> 5;            // 32 float4 per row
        int c4 = i & 31;
        float4 v = ((const float4*)hb)[h * 32 + c4];
        __half2 p0 = __floats2half2_rn(v.x, v.y);
        __half2 p1 = __floats2half2_rn(v.z, v.w);
        __half2* dst = (__half2*)&hist_s[h * LDH + c4 * 4];
        dst[0] = p0;
        dst[1] = p1;
    }

    // ---- c1[j] = b1[j] + sum_k cand[b][k] * W1[128+k][j] ----
    if (tid < HID) {
        const float* cb = cand + (size_t)b * EMB;
        float acc = b1[tid];
        #pragma unroll 8
        for (int k = 0; k < EMB; ++k)
            acc = fmaf(cb[k], W1[(EMB + k) * HID + tid], acc);
        c1_s[tid] = acc;
    }
    __syncthreads();

    // ---- scoring: one history row per lane ----
    if (tid < NH) {
        float h1[HID];
        #pragma unroll
        for (int j = 0; j < HID; ++j) h1[j] = c1_s[j];

        const __half* xrow = &hist_s[tid * LDH];
        for (int k = 0; k < EMB; k += 2) {
            float2 x = __half22float2(*(const __half2*)&xrow[k]);
            #pragma unroll
            for (int j = 0; j < HID; ++j)
                h1[j] = fmaf(x.x, W1[k * HID + j], h1[j]);        // wave-uniform -> s_load
            #pragma unroll
            for (int j = 0; j < HID; ++j)
                h1[j] = fmaf(x.y, W1[(k + 1) * HID + j], h1[j]);
        }

        float h2[HID / 2];
        #pragma unroll
        for (int m = 0; m < HID / 2; ++m) h2[m] = b2[m];
        #pragma unroll 4
        for (int j = 0; j < HID; ++j) {
            float hj = fmaxf(h1[j], 0.f);
            #pragma unroll
            for (int m = 0; m < HID / 2; ++m)
                h2[m] = fmaf(hj, W2[j * (HID / 2) + m], h2[m]);
        }

        float s = b3[0];
        #pragma unroll
        for (int m = 0; m < HID / 2; ++m)
            s = fmaf(fmaxf(h2[m], 0.f), W3[m], s);

        s += (1.f - (float)mask[(size_t)b * NH + tid]) * -1e9f;
        attn_s[tid] = s;
    }
    __syncthreads();

    // ---- softmax over 200 scores (wave 0) ----
    if (tid < 64) {
        float s0 = attn_s[tid];
        float s1 = attn_s[64 + tid];
        float s2 = attn_s[128 + tid];
        float s3 = (tid < 8) ? attn_s[192 + tid] : -1e30f;
        float m = fmaxf(fmaxf(s0, s1), fmaxf(s2, s3));
        #pragma unroll
        for (int off = 32; off; off >>= 1) m = fmaxf(m, __shfl_xor(m, off, 64));
        float e0 = __expf(s0 - m);
        float e1 = __expf(s1 - m);
        float e2 = __expf(s2 - m);
        float e3 = (tid < 8) ? __expf(s3 - m) : 0.f;
        float sum = e0 + e1 + e2 + e3;
        #pragma unroll
        for (int off = 32; off; off >>= 1) sum += __shfl_xor(sum, off, 64);
        float inv = 1.f / sum;
        e0 *= inv; e1 *= inv; e2 *= inv; e3 *= inv;
        attn_s[tid] = e0; attn_s[64 + tid] = e1; attn_s[128 + tid] = e2;
        if (tid < 8) attn_s[192 + tid] = e3;
        float* oa = out_attn + (size_t)b * NH;
        oa[tid] = e0; oa[64 + tid] = e1; oa[128 + tid] = e2;
        if (tid < 8) oa[192 + tid] = e3;
    }
    __syncthreads();

    // ---- aggregation: agg[d] = sum_h attn[h] * hist[b][h][d], from fp16 LDS ----
    {
        int c = tid & 63;   // half2 column -> d = 2c, 2c+1
        int g = tid >> 6;   // wave id -> h in [g*50, g*50+50)
        float2 acc = make_float2(0.f, 0.f);
        for (int h = g * 50; h < g * 50 + 50; ++h) {
            float w  = attn_s[h];                                   // broadcast
            float2 v = __half22float2(*(const __half2*)&hist_s[h * LDH + c * 2]);
            acc.x = fmaf(w, v.x, acc.x);
            acc.y = fmaf(w, v.y, acc.y);
        }
        __syncthreads();                    // all hist_s reads done
        float2* red = (float2*)hist_s;      // overlay reduction buffer on hist_s
        red[g * 64 + c] = acc;
        __syncthreads();
        if (tid < 64) {
            float2 r0 = red[tid], r1 = red[64 + tid], r2 = red[128 + tid], r3 = red[192 + tid];
            float2 o = make_float2(r0.x + r1.x + r2.x + r3.x,
                                   r0.y + r1.y + r2.y + r3.y);
            *(float2*)&out_agg[(size_t)b * EMB + tid * 2] = o;
        }
    }
}

extern "C" void kernel_launch(void* const* d_in, const int* in_sizes, int n_in,
                              void* d_out, int out_size, void* d_ws, size_t ws_size,
                              hipStream_t stream) {
    const float* hist = (const float*)d_in[0];
    const float* cand = (const float*)d_in[1];
    const float* W1   = (const float*)d_in[2];
    const float* b1   = (const float*)d_in[3];
    const float* W2   = (const float*)d_in[4];
    const float* b2   = (const float*)d_in[5];
    const float* W3   = (const float*)d_in[6];
    const float* b3   = (const float*)d_in[7];
    const int*   mask = (const int*)d_in[8];

    const int B = in_sizes[0] / (NH * EMB);   // 4096
    float* out_agg  = (float*)d_out;          // [B, EMB]
    float* out_attn = out_agg + (size_t)B * EMB;  // [B, NH]

    attn_agg_kernel<<<B, BT, 0, stream>>>(hist, cand, W1, b1, W2, b2, W3, b3,
                                          mask, out_agg, out_attn);
}

// Round 2
// 625.238 us; speedup vs baseline: 1.6224x; 1.6224x over previous
//
#include <hip/hip_runtime.h>

#define EMB  128
#define HID  64
#define NH   200
#define BT   256
#define LDX  132   // fp16 LDS stride for X: 264 B/row (mult of 8 B, 2-bank rotate -> <=2-way, free)
#define LDH1 68    // fp16 LDS stride for H1: 136 B/row (mult of 8 B, 2-bank rotate)

typedef _Float16 half_t;
typedef half_t half2v __attribute__((ext_vector_type(2)));
typedef half_t half4v __attribute__((ext_vector_type(4)));
typedef half_t half8v __attribute__((ext_vector_type(8)));
typedef float  f32x4  __attribute__((ext_vector_type(4)));

// One block per batch row b. 4 waves.
// Phase 0: stage hist[b] -> LDS fp16 (X_s), W1/W2 MFMA B-frags -> regs, c1 = b1 + cand@W1[128:]
// Phase 1: H1 = relu(X@W1a + c1) via mfma_f32_16x16x32_f16, wave w = N-tile w; H1 -> LDS fp16
// Phase 2: H2 = relu(H1@W2) via MFMA (waves split M-tiles); layer3 dot W3 + shuffle-reduce -> scores
// Phase 3: masked softmax over 200 (wave 0)
// Phase 4: aggregation from X_s
// M-tiling: 13 tiles at offsets 0,16,...,176,184 (last tile overlaps rows 184..191; dup writes
// are same-wave/same-value -> benign; score writes for dup rows are skipped).
__global__ __launch_bounds__(BT, 2) void attn_agg_kernel(
    const float* __restrict__ hist,   // [B, NH, EMB]
    const float* __restrict__ cand,   // [B, EMB]
    const float* __restrict__ W1,     // [2*EMB, HID]
    const float* __restrict__ b1,     // [HID]
    const float* __restrict__ W2,     // [HID, HID/2]
    const float* __restrict__ b2,     // [HID/2]
    const float* __restrict__ W3,     // [HID/2, 1]
    const float* __restrict__ b3,     // [1]  (softmax-invariant: unused)
    const int*   __restrict__ mask,   // [B, NH]
    float* __restrict__ out_agg,      // [B, EMB]
    float* __restrict__ out_attn)     // [B, NH]
{
    __shared__ __align__(16) half_t X_s[NH * LDX];    // 52,800 B
    __shared__ __align__(16) half_t H1_s[NH * LDH1];  // 27,200 B
    __shared__ float c1_s[HID];                        //    256 B
    __shared__ float attn_s[NH];                       //    800 B
    // total 81,056 B -> 2 blocks/CU

    const int b    = blockIdx.x;
    const int tid  = threadIdx.x;
    const int lane = tid & 63;
    const int wid  = tid >> 6;
    const int c16  = lane & 15;   // MFMA: C col / A row(m) / B col(n)
    const int quad = lane >> 4;   // MFMA: k-group / C row-group

    const float* hb = hist + (size_t)b * (NH * EMB);

    // ---- B-fragments of W1 (this wave's N-tile) and W2 (both N-tiles) into registers ----
    // B-frag layout (16x16x32): lane holds B[k = quad*8 + j][n = c16], j=0..7
    half8v w1f[4];   // 4 K-steps over K=128
    #pragma unroll
    for (int ks = 0; ks < 4; ++ks)
        #pragma unroll
        for (int j = 0; j < 8; ++j)
            w1f[ks][j] = (half_t)W1[(ks * 32 + quad * 8 + j) * HID + wid * 16 + c16];

    half8v w2f[2][2];  // [n-tile][k-step], K=64
    #pragma unroll
    for (int nt = 0; nt < 2; ++nt)
        #pragma unroll
        for (int ks = 0; ks < 2; ++ks)
            #pragma unroll
            for (int j = 0; j < 8; ++j)
                w2f[nt][ks][j] = (half_t)W2[(ks * 32 + quad * 8 + j) * (HID / 2) + nt * 16 + c16];

    const float w3a = W3[c16];
    const float w3b = W3[16 + c16];
    const float bb2a = b2[c16];        // b2 for n = c16 (n-tile 0)
    const float bb2b = b2[16 + c16];   // b2 for n = 16+c16 (n-tile 1)

    // ---- stage hist[b] -> X_s fp16 (25 float4 per thread, coalesced) ----
    {
        const float4* src = (const float4*)hb;
        #pragma unroll 5
        for (int t = 0; t < 25; ++t) {
            int i = t * BT + tid;
            int h = i >> 5, c4 = i & 31;
            float4 v = src[i];
            half2v p0 = {(half_t)v.x, (half_t)v.y};
            half2v p1 = {(half_t)v.z, (half_t)v.w};
            *(half2v*)&X_s[h * LDX + c4 * 4]     = p0;
            *(half2v*)&X_s[h * LDX + c4 * 4 + 2] = p1;
        }
    }

    // ---- c1[j] = b1[j] + cand[b] @ W1[128:256, j]  (wave 0) ----
    if (tid < HID) {
        const float* cb = cand + (size_t)b * EMB;
        float acc = b1[tid];
        #pragma unroll 8
        for (int k = 0; k < EMB; ++k)
            acc = fmaf(cb[k], W1[(EMB + k) * HID + tid], acc);
        c1_s[tid] = acc;
    }
    __syncthreads();

    // ---- layer 1: H1 = relu(X @ W1a + c1), wave w = N-tile w ----
    {
        const float c1v = c1_s[wid * 16 + c16];   // column n = wid*16 + c16
        for (int t = 0; t < 13; ++t) {
            const int m0 = (t < 12) ? t * 16 : 184;
            const int row = m0 + c16;             // A: m = c16
            f32x4 acc = {0.f, 0.f, 0.f, 0.f};
            #pragma unroll
            for (int ks = 0; ks < 4; ++ks) {
                const half_t* ap = &X_s[row * LDX + ks * 32 + quad * 8];
                half4v alo = *(const half4v*)ap;
                half4v ahi = *(const half4v*)(ap + 4);
                half8v a = __builtin_shufflevector(alo, ahi, 0, 1, 2, 3, 4, 5, 6, 7);
                acc = __builtin_amdgcn_mfma_f32_16x16x32_f16(a, w1f[ks], acc, 0, 0, 0);
            }
            // C: lane holds col n = wid*16+c16, rows m0 + 4*quad + i
            #pragma unroll
            for (int i = 0; i < 4; ++i) {
                int r = m0 + 4 * quad + i;
                float hv = fmaxf(acc[i] + c1v, 0.f);
                H1_s[r * LDH1 + wid * 16 + c16] = (half_t)hv;
            }
        }
    }
    __syncthreads();

    // ---- layer 2 + 3: scores = relu(H1 @ W2 + b2) @ W3, M-tiles split across waves ----
    for (int t = wid; t < 13; t += 4) {
        const int m0 = (t < 12) ? t * 16 : 184;
        const int row = m0 + c16;
        f32x4 acc0 = {0.f, 0.f, 0.f, 0.f};
        f32x4 acc1 = {0.f, 0.f, 0.f, 0.f};
        #pragma unroll
        for (int ks = 0; ks < 2; ++ks) {
            const half_t* ap = &H1_s[row * LDH1 + ks * 32 + quad * 8];
            half4v alo = *(const half4v*)ap;
            half4v ahi = *(const half4v*)(ap + 4);
            half8v a = __builtin_shufflevector(alo, ahi, 0, 1, 2, 3, 4, 5, 6, 7);
            acc0 = __builtin_amdgcn_mfma_f32_16x16x32_f16(a, w2f[0][ks], acc0, 0, 0, 0);
            acc1 = __builtin_amdgcn_mfma_f32_16x16x32_f16(a, w2f[1][ks], acc1, 0, 0, 0);
        }
        float sp[4];
        #pragma unroll
        for (int i = 0; i < 4; ++i)
            sp[i] = fmaxf(acc0[i] + bb2a, 0.f) * w3a + fmaxf(acc1[i] + bb2b, 0.f) * w3b;
        #pragma unroll
        for (int m = 1; m < 16; m <<= 1)
            #pragma unroll
            for (int i = 0; i < 4; ++i)
                sp[i] += __shfl_xor(sp[i], m, 64);
        if (c16 == 0) {
            const int lo = (t == 12) ? 192 : m0;  // skip dup rows 184..191 in last tile
            #pragma unroll
            for (int i = 0; i < 4; ++i) {
                int r = m0 + 4 * quad + i;
                if (r >= lo) attn_s[r] = sp[i];
            }
        }
    }
    __syncthreads();

    // ---- masked softmax over 200 (wave 0) ----
    if (tid < 64) {
        const int* mb = mask + (size_t)b * NH;
        float s0 = attn_s[tid]       + (1.f - (float)mb[tid])       * -1e9f;
        float s1 = attn_s[64 + tid]  + (1.f - (float)mb[64 + tid])  * -1e9f;
        float s2 = attn_s[128 + tid] + (1.f - (float)mb[128 + tid]) * -1e9f;
        float s3 = (tid < 8) ? attn_s[192 + tid] + (1.f - (float)mb[192 + tid]) * -1e9f : -1e30f;
        float m = fmaxf(fmaxf(s0, s1), fmaxf(s2, s3));
        #pragma unroll
        for (int off = 32; off; off >>= 1) m = fmaxf(m, __shfl_xor(m, off, 64));
        float e0 = __expf(s0 - m);
        float e1 = __expf(s1 - m);
        float e2 = __expf(s2 - m);
        float e3 = (tid < 8) ? __expf(s3 - m) : 0.f;
        float sum = e0 + e1 + e2 + e3;
        #pragma unroll
        for (int off = 32; off; off >>= 1) sum += __shfl_xor(sum, off, 64);
        float inv = 1.f / sum;
        e0 *= inv; e1 *= inv; e2 *= inv; e3 *= inv;
        attn_s[tid] = e0; attn_s[64 + tid] = e1; attn_s[128 + tid] = e2;
        if (tid < 8) attn_s[192 + tid] = e3;
        float* oa = out_attn + (size_t)b * NH;
        oa[tid] = e0; oa[64 + tid] = e1; oa[128 + tid] = e2;
        if (tid < 8) oa[192 + tid] = e3;
    }
    __syncthreads();

    // ---- aggregation: agg[d] = sum_h attn[h] * hist[b][h][d], from fp16 X_s ----
    {
        int c = tid & 63;   // half2 column -> d = 2c, 2c+1
        int g = wid;        // wave id -> h in [g*50, g*50+50)
        float2 acc = make_float2(0.f, 0.f);
        for (int h = g * 50; h < g * 50 + 50; ++h) {
            float w = attn_s[h];
            half2v v = *(const half2v*)&X_s[h * LDX + c * 2];
            acc.x = fmaf(w, (float)v[0], acc.x);
            acc.y = fmaf(w, (float)v[1], acc.y);
        }
        __syncthreads();                 // all X_s reads done
        float2* red = (float2*)X_s;      // overlay reduction buffer
        red[g * 64 + c] = acc;
        __syncthreads();
        if (tid < 64) {
            float2 r0 = red[tid], r1 = red[64 + tid], r2 = red[128 + tid], r3 = red[192 + tid];
            float2 o = make_float2(r0.x + r1.x + r2.x + r3.x,
                                   r0.y + r1.y + r2.y + r3.y);
            *(float2*)&out_agg[(size_t)b * EMB + tid * 2] = o;
        }
    }
}

extern "C" void kernel_launch(void* const* d_in, const int* in_sizes, int n_in,
                              void* d_out, int out_size, void* d_ws, size_t ws_size,
                              hipStream_t stream) {
    const float* hist = (const float*)d_in[0];
    const float* cand = (const float*)d_in[1];
    const float* W1   = (const float*)d_in[2];
    const float* b1   = (const float*)d_in[3];
    const float* W2   = (const float*)d_in[4];
    const float* b2   = (const float*)d_in[5];
    const float* W3   = (const float*)d_in[6];
    const float* b3   = (const float*)d_in[7];
    const int*   mask = (const int*)d_in[8];

    const int B = in_sizes[0] / (NH * EMB);       // 4096
    float* out_agg  = (float*)d_out;              // [B, EMB]
    float* out_attn = out_agg + (size_t)B * EMB;  // [B, NH]

    attn_agg_kernel<<<B, BT, 0, stream>>>(hist, cand, W1, b1, W2, b2, W3, b3,
                                          mask, out_agg, out_attn);
}

// Round 3
// 572.711 us; speedup vs baseline: 1.7712x; 1.0917x over previous
//
#include <hip/hip_runtime.h>

#define EMB  128
#define HID  64
#define NH   200
#define BT   256
#define LDX  132   // fp16 LDS stride for X: 264 B/row (2-bank rotate -> <=2-way, free)
#define LDH1 68    // fp16 LDS stride for H1: 136 B/row

#define WS_FRAG_BYTES 32768   // 256 threads * 8 frags * 16 B

typedef _Float16 half_t;
typedef half_t half2v __attribute__((ext_vector_type(2)));
typedef half_t half4v __attribute__((ext_vector_type(4)));
typedef half_t half8v __attribute__((ext_vector_type(8)));
typedef float  f32x4  __attribute__((ext_vector_type(4)));

// ---------------------------------------------------------------------------
// Precompute kernel (runs once per launch, ~10 us):
//  blocks [0, nblk_c1): c1_all[b][j] = b1[j] + cand[b] @ W1[128:256, j]   (4 b/block)
//  block nblk_c1:       per-tid MFMA B-fragments of W1a / W2 -> frag_ws (32 KB,
//                       laid out so the main kernel's loads are fully coalesced)
// ---------------------------------------------------------------------------
__global__ __launch_bounds__(BT) void precomp_kernel(
    const float* __restrict__ W1, const float* __restrict__ b1,
    const float* __restrict__ W2, const float* __restrict__ cand,
    half8v* __restrict__ frag_ws, float* __restrict__ c1_ws, int nblk_c1)
{
    const int tid = threadIdx.x;
    if ((int)blockIdx.x == nblk_c1) {
        const int lane = tid & 63, wid = tid >> 6;
        const int c16 = lane & 15, quad = lane >> 4;
        half8v f[8];
        // B-frag (16x16x32): lane holds B[k = quad*8 + j][n = c16], j=0..7
        #pragma unroll
        for (int ks = 0; ks < 4; ++ks)
            #pragma unroll
            for (int j = 0; j < 8; ++j)
                f[ks][j] = (half_t)W1[(ks * 32 + quad * 8 + j) * HID + wid * 16 + c16];
        #pragma unroll
        for (int nt = 0; nt < 2; ++nt)
            #pragma unroll
            for (int ks = 0; ks < 2; ++ks)
                #pragma unroll
                for (int j = 0; j < 8; ++j)
                    f[4 + nt * 2 + ks][j] =
                        (half_t)W2[(ks * 32 + quad * 8 + j) * (HID / 2) + nt * 16 + c16];
        #pragma unroll
        for (int i = 0; i < 8; ++i) frag_ws[tid * 8 + i] = f[i];
    } else {
        __shared__ float W1b_s[EMB * HID];   // 32 KB (W1 rows 128..255 are contiguous)
        __shared__ float cand_s[4 * EMB];
        const int b0 = blockIdx.x * 4;
        for (int i = tid; i < EMB * HID; i += BT) W1b_s[i] = W1[EMB * HID + i];
        for (int i = tid; i < 4 * EMB; i += BT) cand_s[i] = cand[(size_t)b0 * EMB + i];
        __syncthreads();
        const int bl = tid >> 6, j = tid & 63;
        float acc = b1[j];
        #pragma unroll 8
        for (int k = 0; k < EMB; ++k)
            acc = fmaf(cand_s[bl * EMB + k], W1b_s[k * HID + j], acc);
        c1_ws[(size_t)(b0 + bl) * HID + j] = acc;
    }
}

// ---------------------------------------------------------------------------
// Main kernel: one block per batch row b. 4 waves, 2 blocks/CU.
// Phase 0: stage hist[b] -> LDS fp16 (X_s); frags + c1 row via coalesced ws loads
// Phase 1: H1 = relu(X@W1a + c1) via mfma_f32_16x16x32_f16 (wave = N-tile)
// Phase 2: scores = relu(H1@W2 + b2)@W3 via MFMA + shuffle-reduce
// Phase 3: masked softmax over 200 (wave 0)
// Phase 4: aggregation from fp16 X_s
// ---------------------------------------------------------------------------
__global__ __launch_bounds__(BT, 2) void attn_agg_kernel(
    const float* __restrict__ hist,     // [B, NH, EMB]
    const half8v* __restrict__ frag_ws, // [256*8] per-tid fragments
    const float* __restrict__ c1_ws,    // [B, HID]
    const float* __restrict__ b2,       // [HID/2]
    const float* __restrict__ W3,       // [HID/2, 1]
    const int*   __restrict__ mask,     // [B, NH]
    float* __restrict__ out_agg,        // [B, EMB]
    float* __restrict__ out_attn)       // [B, NH]
{
    __shared__ __align__(16) half_t X_s[NH * LDX];    // 52,800 B
    __shared__ __align__(16) half_t H1_s[NH * LDH1];  // 27,200 B
    __shared__ float c1_s[HID];
    __shared__ float attn_s[NH];
    // total ~81 KB -> 2 blocks/CU

    const int b    = blockIdx.x;
    const int tid  = threadIdx.x;
    const int lane = tid & 63;
    const int wid  = tid >> 6;
    const int c16  = lane & 15;
    const int quad = lane >> 4;

    const float* hb = hist + (size_t)b * (NH * EMB);

    // ---- coalesced fragment loads (8 x 16 B per thread, L2-resident table) ----
    const half8v* fw = frag_ws + tid * 8;
    half8v w1f[4];
    w1f[0] = fw[0]; w1f[1] = fw[1]; w1f[2] = fw[2]; w1f[3] = fw[3];
    half8v w2f[2][2];
    w2f[0][0] = fw[4]; w2f[0][1] = fw[5]; w2f[1][0] = fw[6]; w2f[1][1] = fw[7];

    const float w3a  = W3[c16];
    const float w3b  = W3[16 + c16];
    const float bb2a = b2[c16];
    const float bb2b = b2[16 + c16];

    // ---- c1 row (coalesced, precomputed) ----
    if (tid < HID) c1_s[tid] = c1_ws[(size_t)b * HID + tid];

    // ---- stage hist[b] -> X_s fp16 (25 float4 per thread, coalesced) ----
    {
        const float4* src = (const float4*)hb;
        #pragma unroll 5
        for (int t = 0; t < 25; ++t) {
            int i = t * BT + tid;
            int h = i >> 5, c4 = i & 31;
            float4 v = src[i];
            half2v p0 = {(half_t)v.x, (half_t)v.y};
            half2v p1 = {(half_t)v.z, (half_t)v.w};
            *(half2v*)&X_s[h * LDX + c4 * 4]     = p0;
            *(half2v*)&X_s[h * LDX + c4 * 4 + 2] = p1;
        }
    }
    __syncthreads();

    // ---- layer 1: H1 = relu(X @ W1a + c1), wave w = N-tile w ----
    {
        const float c1v = c1_s[wid * 16 + c16];
        for (int t = 0; t < 13; ++t) {
            const int m0 = (t < 12) ? t * 16 : 184;
            const int row = m0 + c16;
            f32x4 acc = {0.f, 0.f, 0.f, 0.f};
            #pragma unroll
            for (int ks = 0; ks < 4; ++ks) {
                const half_t* ap = &X_s[row * LDX + ks * 32 + quad * 8];
                half4v alo = *(const half4v*)ap;
                half4v ahi = *(const half4v*)(ap + 4);
                half8v a = __builtin_shufflevector(alo, ahi, 0, 1, 2, 3, 4, 5, 6, 7);
                acc = __builtin_amdgcn_mfma_f32_16x16x32_f16(a, w1f[ks], acc, 0, 0, 0);
            }
            #pragma unroll
            for (int i = 0; i < 4; ++i) {
                int r = m0 + 4 * quad + i;
                float hv = fmaxf(acc[i] + c1v, 0.f);
                H1_s[r * LDH1 + wid * 16 + c16] = (half_t)hv;
            }
        }
    }
    __syncthreads();

    // ---- layer 2 + 3: scores, M-tiles split across waves ----
    for (int t = wid; t < 13; t += 4) {
        const int m0 = (t < 12) ? t * 16 : 184;
        const int row = m0 + c16;
        f32x4 acc0 = {0.f, 0.f, 0.f, 0.f};
        f32x4 acc1 = {0.f, 0.f, 0.f, 0.f};
        #pragma unroll
        for (int ks = 0; ks < 2; ++ks) {
            const half_t* ap = &H1_s[row * LDH1 + ks * 32 + quad * 8];
            half4v alo = *(const half4v*)ap;
            half4v ahi = *(const half4v*)(ap + 4);
            half8v a = __builtin_shufflevector(alo, ahi, 0, 1, 2, 3, 4, 5, 6, 7);
            acc0 = __builtin_amdgcn_mfma_f32_16x16x32_f16(a, w2f[0][ks], acc0, 0, 0, 0);
            acc1 = __builtin_amdgcn_mfma_f32_16x16x32_f16(a, w2f[1][ks], acc1, 0, 0, 0);
        }
        float sp[4];
        #pragma unroll
        for (int i = 0; i < 4; ++i)
            sp[i] = fmaxf(acc0[i] + bb2a, 0.f) * w3a + fmaxf(acc1[i] + bb2b, 0.f) * w3b;
        #pragma unroll
        for (int m = 1; m < 16; m <<= 1)
            #pragma unroll
            for (int i = 0; i < 4; ++i)
                sp[i] += __shfl_xor(sp[i], m, 64);
        if (c16 == 0) {
            const int lo = (t == 12) ? 192 : m0;   // skip dup rows 184..191
            #pragma unroll
            for (int i = 0; i < 4; ++i) {
                int r = m0 + 4 * quad + i;
                if (r >= lo) attn_s[r] = sp[i];
            }
        }
    }
    __syncthreads();

    // ---- masked softmax over 200 (wave 0) ----
    if (tid < 64) {
        const int* mb = mask + (size_t)b * NH;
        float s0 = attn_s[tid]       + (1.f - (float)mb[tid])       * -1e9f;
        float s1 = attn_s[64 + tid]  + (1.f - (float)mb[64 + tid])  * -1e9f;
        float s2 = attn_s[128 + tid] + (1.f - (float)mb[128 + tid]) * -1e9f;
        float s3 = (tid < 8) ? attn_s[192 + tid] + (1.f - (float)mb[192 + tid]) * -1e9f : -1e30f;
        float m = fmaxf(fmaxf(s0, s1), fmaxf(s2, s3));
        #pragma unroll
        for (int off = 32; off; off >>= 1) m = fmaxf(m, __shfl_xor(m, off, 64));
        float e0 = __expf(s0 - m);
        float e1 = __expf(s1 - m);
        float e2 = __expf(s2 - m);
        float e3 = (tid < 8) ? __expf(s3 - m) : 0.f;
        float sum = e0 + e1 + e2 + e3;
        #pragma unroll
        for (int off = 32; off; off >>= 1) sum += __shfl_xor(sum, off, 64);
        float inv = 1.f / sum;
        e0 *= inv; e1 *= inv; e2 *= inv; e3 *= inv;
        attn_s[tid] = e0; attn_s[64 + tid] = e1; attn_s[128 + tid] = e2;
        if (tid < 8) attn_s[192 + tid] = e3;
        float* oa = out_attn + (size_t)b * NH;
        oa[tid] = e0; oa[64 + tid] = e1; oa[128 + tid] = e2;
        if (tid < 8) oa[192 + tid] = e3;
    }
    __syncthreads();

    // ---- aggregation: agg[d] = sum_h attn[h] * hist[b][h][d], from fp16 X_s ----
    {
        int c = tid & 63;
        int g = wid;
        float2 acc = make_float2(0.f, 0.f);
        for (int h = g * 50; h < g * 50 + 50; ++h) {
            float w = attn_s[h];
            half2v v = *(const half2v*)&X_s[h * LDX + c * 2];
            acc.x = fmaf(w, (float)v[0], acc.x);
            acc.y = fmaf(w, (float)v[1], acc.y);
        }
        __syncthreads();
        float2* red = (float2*)X_s;
        red[g * 64 + c] = acc;
        __syncthreads();
        if (tid < 64) {
            float2 r0 = red[tid], r1 = red[64 + tid], r2 = red[128 + tid], r3 = red[192 + tid];
            float2 o = make_float2(r0.x + r1.x + r2.x + r3.x,
                                   r0.y + r1.y + r2.y + r3.y);
            *(float2*)&out_agg[(size_t)b * EMB + tid * 2] = o;
        }
    }
}

extern "C" void kernel_launch(void* const* d_in, const int* in_sizes, int n_in,
                              void* d_out, int out_size, void* d_ws, size_t ws_size,
                              hipStream_t stream) {
    const float* hist = (const float*)d_in[0];
    const float* cand = (const float*)d_in[1];
    const float* W1   = (const float*)d_in[2];
    const float* b1   = (const float*)d_in[3];
    const float* W2   = (const float*)d_in[4];
    const float* b2   = (const float*)d_in[5];
    const float* W3   = (const float*)d_in[6];
    const int*   mask = (const int*)d_in[8];

    const int B = in_sizes[0] / (NH * EMB);       // 4096
    float* out_agg  = (float*)d_out;              // [B, EMB]
    float* out_attn = out_agg + (size_t)B * EMB;  // [B, NH]

    half8v* frag_ws = (half8v*)d_ws;
    float*  c1_ws   = (float*)((char*)d_ws + WS_FRAG_BYTES);

    const int nblk_c1 = B / 4;
    precomp_kernel<<<nblk_c1 + 1, BT, 0, stream>>>(W1, b1, W2, cand, frag_ws, c1_ws, nblk_c1);
    attn_agg_kernel<<<B, BT, 0, stream>>>(hist, frag_ws, c1_ws, b2, W3, mask,
                                          out_agg, out_attn);
}